// Round 11
// baseline (3717.622 us; speedup 1.0000x reference)
//
#include <hip/hip_runtime.h>

typedef unsigned short ushortT;
typedef short bf16x8 __attribute__((ext_vector_type(8)));
typedef float f32x4 __attribute__((ext_vector_type(4)));
typedef unsigned int u32x4 __attribute__((ext_vector_type(4)));

// EqProp free phase, B=4096, layers [10,512,512 | x=784 clamped], T=30, DT=0.5.
// States stay in [0,1] => rho(s)=s, rhop(s)=1. Step: n = clip(0.5 s + 0.5 z),
//   z1 = s2@W1^T + b1 + s0@W0;  z2 = c2 + s1@W1;  z0 = s1@W0^T + b0.
// ROW-OWNERSHIP persistent design: batch rows are independent across steps ->
// 128 blocks x 32 rows each run all 30 steps locally. State in LDS (+ old
// state in regs), weights streamed from L2 in MFMA-fragment-packed layout
// (1KB coalesced loads), c2 fp32 from L2. No grid sync, no fences, 3 launches.
// Numerics identical to R6 (bf16 state, split hi/lo bf16 W1, fp32 c2): 0.0117.
#define CSTR 1034

__device__ __forceinline__ ushortT f2b(float f) {
    union { float f; unsigned u; } v; v.f = f;
    return (ushortT)((v.u + 0x7FFFu + ((v.u >> 16) & 1u)) >> 16);  // RNE
}
__device__ __forceinline__ float b2f(ushortT b) {
    union { unsigned u; float f; } v; v.u = ((unsigned)b) << 16;
    return v.f;
}
__device__ __forceinline__ void split2(float f, ushortT& h, ushortT& l) {
    h = f2b(f);
    l = f2b(f - b2f(h));
}

#define MFMA(a, b, c) __builtin_amdgcn_mfma_f32_16x16x32_bf16(a, b, c, 0, 0, 0)
#define BCAST(x) __builtin_bit_cast(bf16x8, x)

// ---------------- weight prep: emit MFMA-fragment-packed arrays ----------------
// Fragment (nf, kw, lane): n = nf*16 + (lane&15), k = kw*32 + (lane>>4)*8 + e.
// pkZ1 = W1[n][k] (z1: B=W1^T read row-wise), pkZ2 = W1[k][n] (z2: B=W1),
// pkS0 = W0[k][n] (k<10, K=32 window), pkZ0 = W0[n][k] (n<10).
__global__ __launch_bounds__(256) void k_prep2(const float* __restrict__ W1,
                                               const float* __restrict__ W0,
                                               u32x4* __restrict__ pkZ1h,
                                               u32x4* __restrict__ pkZ1l,
                                               u32x4* __restrict__ pkZ2h,
                                               u32x4* __restrict__ pkZ2l,
                                               u32x4* __restrict__ pkS0,
                                               u32x4* __restrict__ pkZ0) {
    const int idx = blockIdx.x * 256 + threadIdx.x;
    if (idx < 32768) {                 // main W1 frags: nf 0..31, kw 0..15, lane
        const int lane = idx & 63, rest = idx >> 6;
        const int kw = rest & 15, nf = rest >> 4;
        const int n = nf * 16 + (lane & 15);
        const int k0 = kw * 32 + (lane >> 4) * 8;
        union { ushortT us[8]; u32x4 v; } h1, l1, h2, l2;
#pragma unroll
        for (int e = 0; e < 8; ++e) {
            split2(W1[(size_t)n * 512 + k0 + e], h1.us[e], l1.us[e]);
            split2(W1[(size_t)(k0 + e) * 512 + n], h2.us[e], l2.us[e]);
        }
        pkZ1h[idx] = h1.v;  pkZ1l[idx] = l1.v;
        pkZ2h[idx] = h2.v;  pkZ2l[idx] = l2.v;
    } else if (idx < 32768 + 2048) {   // pkS0: nf 0..31, lane
        const int f = idx - 32768;
        const int lane = f & 63, nf = f >> 6;
        const int n = nf * 16 + (lane & 15);
        const int kb = (lane >> 4) * 8;
        union { ushortT us[8]; u32x4 v; } pk;
#pragma unroll
        for (int e = 0; e < 8; ++e) {
            int k = kb + e;
            pk.us[e] = (k < 10) ? f2b(W0[(size_t)k * 512 + n]) : (ushortT)0;
        }
        pkS0[f] = pk.v;
    } else if (idx < 32768 + 2048 + 1024) {  // pkZ0: kw 0..15, lane
        const int f = idx - 32768 - 2048;
        const int lane = f & 63, kw = f >> 6;
        const int n = lane & 15;
        const int kb = kw * 32 + (lane >> 4) * 8;
        union { ushortT us[8]; u32x4 v; } pk;
#pragma unroll
        for (int e = 0; e < 8; ++e)
            pk.us[e] = (n < 10) ? f2b(W0[(size_t)n * 512 + kb + e]) : (ushortT)0;
        pkZ0[f] = pk.v;
    }
}

// ---------------- c2 = rho(x) @ W2^T + b2 via split-bf16 MFMA (proven) ----------------
__global__ __launch_bounds__(256) void k_c2(const float* __restrict__ x,
                                            const float* __restrict__ W2,
                                            const float* __restrict__ b2,
                                            float* __restrict__ c2) {
    __shared__ u32x4 cs[2048];
    u32x4* xHi = cs;
    u32x4* xLo = cs + 512;
    u32x4* wHi = cs + 1024;
    u32x4* wLo = cs + 1536;
    const int bid = blockIdx.x, t = threadIdx.x;
    const int lane = t & 63, w = t >> 6, l15 = lane & 15, l4 = lane >> 4;
    const int bm2 = (bid >> 3) * 64, bn2 = (bid & 7) * 64;
    const int mB2 = (w >> 1) * 32, nB2 = (w & 1) * 32;
    const int sr2 = t >> 2, ub = (t & 3) * 2;
    f32x4 accC[2][2];
#pragma unroll
    for (int i = 0; i < 2; ++i)
#pragma unroll
        for (int j = 0; j < 2; ++j) { f32x4 z = {0.f, 0.f, 0.f, 0.f}; accC[i][j] = z; }
    for (int k0 = 0; k0 < 784; k0 += 64) {
#pragma unroll
        for (int j = 0; j < 2; ++j) {
            int u = ub + j;
            bool valid = (k0 + u * 8 + 8 <= 784);
            union { ushortT us[8]; u32x4 v; } ph, pl, qh, ql;
            if (valid) {
                const float* srcx = x  + (size_t)(bm2 + sr2) * 784 + k0 + u * 8;
                const float* srcw = W2 + (size_t)(bn2 + sr2) * 784 + k0 + u * 8;
#pragma unroll
                for (int e = 0; e < 8; ++e) {
                    float cx = fminf(fmaxf(srcx[e], 0.f), 1.f);
                    split2(cx, ph.us[e], pl.us[e]);
                    split2(srcw[e], qh.us[e], ql.us[e]);
                }
            } else {
#pragma unroll
                for (int e = 0; e < 8; ++e) { ph.us[e]=0; pl.us[e]=0; qh.us[e]=0; ql.us[e]=0; }
            }
            int sw = u ^ (sr2 & 7);
            xHi[sr2 * 8 + sw] = ph.v;  xLo[sr2 * 8 + sw] = pl.v;
            wHi[sr2 * 8 + sw] = qh.v;  wLo[sr2 * 8 + sw] = ql.v;
        }
        __syncthreads();
        int kwMax = (k0 == 768) ? 1 : 2;
        for (int kw = 0; kw < kwMax; ++kw) {
            bf16x8 ah[2], al[2], bh[2], bl[2];
#pragma unroll
            for (int i = 0; i < 2; ++i) {
                int m = mB2 + i * 16 + l15;
                int uu = (kw * 4 + l4) ^ (m & 7);
                ah[i] = BCAST(xHi[m * 8 + uu]);
                al[i] = BCAST(xLo[m * 8 + uu]);
                int n = nB2 + i * 16 + l15;
                int uv = (kw * 4 + l4) ^ (n & 7);
                bh[i] = BCAST(wHi[n * 8 + uv]);
                bl[i] = BCAST(wLo[n * 8 + uv]);
            }
#pragma unroll
            for (int i = 0; i < 2; ++i)
#pragma unroll
                for (int jj = 0; jj < 2; ++jj) {
                    accC[i][jj] = MFMA(ah[i], bh[jj], accC[i][jj]);
                    accC[i][jj] = MFMA(al[i], bh[jj], accC[i][jj]);
                    accC[i][jj] = MFMA(ah[i], bl[jj], accC[i][jj]);
                }
        }
        __syncthreads();
    }
#pragma unroll
    for (int mi = 0; mi < 2; ++mi)
#pragma unroll
        for (int ni = 0; ni < 2; ++ni)
#pragma unroll
            for (int q = 0; q < 4; ++q) {
                int row = bm2 + mB2 + mi * 16 + l4 * 4 + q;
                int col = bn2 + nB2 + ni * 16 + l15;
                c2[(size_t)row * 512 + col] = accC[mi][ni][q] + b2[col];
            }
}

// ================= row-persistent main kernel =================
// 128 blocks x 512 threads (8 waves). Block owns rows [bid*32, bid*32+32).
// Wave w owns output cols [w*64, w*64+64) of BOTH s1 (z1) and s2 (z2).
// State: s1,s2 in LDS (bf16, swizzled 16B units); s0 in LDS [32][32] bf16.
// Old state for the update rule lives in REGISTERS (same thread owns same
// (row,col) across all steps). Weights read from packed global (L2-resident).
__global__ __launch_bounds__(512, 1) void k_main(const u32x4* __restrict__ pkZ1h,
                                                 const u32x4* __restrict__ pkZ1l,
                                                 const u32x4* __restrict__ pkZ2h,
                                                 const u32x4* __restrict__ pkZ2l,
                                                 const u32x4* __restrict__ pkS0,
                                                 const u32x4* __restrict__ pkZ0,
                                                 const float* __restrict__ b0,
                                                 const float* __restrict__ b1,
                                                 const float* __restrict__ c2,
                                                 float* __restrict__ outF) {
    __shared__ u32x4 smem[4224];        // 67.6 KB (static >64KB OK per R6)
    u32x4* s2S = smem;                  // 2048: s2 [32 rows][64 units], swz u^(row&7)
    u32x4* s1S = smem + 2048;           // 2048: s1 same layout
    u32x4* s0S = smem + 4096;           //  128: s0 [32 rows][4 units] = [32][32] bf16

    const int t = threadIdx.x, bm = blockIdx.x * 32;
    const int lane = t & 63, w = t >> 6, l15 = lane & 15, l4 = lane >> 4;
    const int cb = w * 64;
    const bool w0 = (w == 0);

    for (int i = t; i < 4224; i += 512) { u32x4 z = {0u,0u,0u,0u}; smem[i] = z; }

    float b1r[4];
#pragma unroll
    for (int nf = 0; nf < 4; ++nf) b1r[nf] = b1[cb + nf * 16 + l15];
    const float b0v = (w0 && l15 < 10) ? b0[l15] : 0.f;

    float va1[4][2][4], va2[4][2][4], vaZ[2][4];
#pragma unroll
    for (int nf = 0; nf < 4; ++nf)
#pragma unroll
        for (int mi = 0; mi < 2; ++mi)
#pragma unroll
            for (int q = 0; q < 4; ++q) { va1[nf][mi][q] = 0.f; va2[nf][mi][q] = 0.f; }
#pragma unroll
    for (int mi = 0; mi < 2; ++mi)
#pragma unroll
        for (int q = 0; q < 4; ++q) vaZ[mi][q] = 0.f;

    __syncthreads();

    for (int ts = 0; ts < 30; ++ts) {
        const bool fin = (ts == 29);

        // ---------- z1 = s2 @ W1^T (+ s0 @ W0 window) ----------
        f32x4 acc1[4][2];
#pragma unroll
        for (int nf = 0; nf < 4; ++nf)
#pragma unroll
            for (int mi = 0; mi < 2; ++mi) { f32x4 z = {0.f,0.f,0.f,0.f}; acc1[nf][mi] = z; }
#pragma unroll
        for (int kw = 0; kw < 16; ++kw) {
            bf16x8 am[2];
#pragma unroll
            for (int mi = 0; mi < 2; ++mi) {
                int m = mi * 16 + l15;
                am[mi] = BCAST(s2S[m * 64 + ((kw * 4 + l4) ^ (m & 7))]);
            }
#pragma unroll
            for (int nf = 0; nf < 4; ++nf) {
                int bi = ((w * 4 + nf) * 16 + kw) * 64 + lane;
                bf16x8 bh = BCAST(pkZ1h[bi]);
                bf16x8 bl = BCAST(pkZ1l[bi]);
#pragma unroll
                for (int mi = 0; mi < 2; ++mi) {
                    acc1[nf][mi] = MFMA(am[mi], bh, acc1[nf][mi]);
                    acc1[nf][mi] = MFMA(am[mi], bl, acc1[nf][mi]);
                }
            }
        }
        {   // s0 @ W0 extra K=32 window
            bf16x8 a0[2];
#pragma unroll
            for (int mi = 0; mi < 2; ++mi) {
                int m = mi * 16 + l15;
                a0[mi] = BCAST(s0S[m * 4 + l4]);
            }
#pragma unroll
            for (int nf = 0; nf < 4; ++nf) {
                bf16x8 bs = BCAST(pkS0[(w * 4 + nf) * 64 + lane]);
#pragma unroll
                for (int mi = 0; mi < 2; ++mi)
                    acc1[nf][mi] = MFMA(a0[mi], bs, acc1[nf][mi]);
            }
        }
        // register-only s1 update (LDS write deferred past z2's s1 reads)
#pragma unroll
        for (int nf = 0; nf < 4; ++nf)
#pragma unroll
            for (int mi = 0; mi < 2; ++mi)
#pragma unroll
                for (int q = 0; q < 4; ++q) {
                    float v = 0.5f * va1[nf][mi][q] + 0.5f * (acc1[nf][mi][q] + b1r[nf]);
                    va1[nf][mi][q] = fminf(fmaxf(v, 0.f), 1.f);
                }

        // ---------- z2 = c2 + s1 @ W1  (+ z0 = s1 @ W0^T on wave 0) ----------
        f32x4 acc2[4][2], accZ[2];
#pragma unroll
        for (int nf = 0; nf < 4; ++nf)
#pragma unroll
            for (int mi = 0; mi < 2; ++mi) { f32x4 z = {0.f,0.f,0.f,0.f}; acc2[nf][mi] = z; }
#pragma unroll
        for (int mi = 0; mi < 2; ++mi) { f32x4 z = {0.f,0.f,0.f,0.f}; accZ[mi] = z; }
#pragma unroll
        for (int kw = 0; kw < 16; ++kw) {
            bf16x8 am[2];
#pragma unroll
            for (int mi = 0; mi < 2; ++mi) {
                int m = mi * 16 + l15;
                am[mi] = BCAST(s1S[m * 64 + ((kw * 4 + l4) ^ (m & 7))]);
            }
#pragma unroll
            for (int nf = 0; nf < 4; ++nf) {
                int bi = ((w * 4 + nf) * 16 + kw) * 64 + lane;
                bf16x8 bh = BCAST(pkZ2h[bi]);
                bf16x8 bl = BCAST(pkZ2l[bi]);
#pragma unroll
                for (int mi = 0; mi < 2; ++mi) {
                    acc2[nf][mi] = MFMA(am[mi], bh, acc2[nf][mi]);
                    acc2[nf][mi] = MFMA(am[mi], bl, acc2[nf][mi]);
                }
            }
            if (w0) {
                bf16x8 bz = BCAST(pkZ0[kw * 64 + lane]);
#pragma unroll
                for (int mi = 0; mi < 2; ++mi)
                    accZ[mi] = MFMA(am[mi], bz, accZ[mi]);
            }
        }
        // s2 update (c2 bias from global, L2-resident)
#pragma unroll
        for (int nf = 0; nf < 4; ++nf)
#pragma unroll
            for (int mi = 0; mi < 2; ++mi)
#pragma unroll
                for (int q = 0; q < 4; ++q) {
                    int row = mi * 16 + l4 * 4 + q;
                    int col = cb + nf * 16 + l15;
                    float cv = c2[(size_t)(bm + row) * 512 + col];
                    float v = 0.5f * va2[nf][mi][q] + 0.5f * (acc2[nf][mi][q] + cv);
                    va2[nf][mi][q] = fminf(fmaxf(v, 0.f), 1.f);
                }
        if (w0) {
#pragma unroll
            for (int mi = 0; mi < 2; ++mi)
#pragma unroll
                for (int q = 0; q < 4; ++q) {
                    float v = 0.5f * vaZ[mi][q] + 0.5f * (accZ[mi][q] + b0v);
                    vaZ[mi][q] = fminf(fmaxf(v, 0.f), 1.f);
                }
        }

        __syncthreads();   // all GEMM reads of old state done
        if (!fin) {
            ushortT* s1u = (ushortT*)s1S;
            ushortT* s2u = (ushortT*)s2S;
#pragma unroll
            for (int nf = 0; nf < 4; ++nf)
#pragma unroll
                for (int mi = 0; mi < 2; ++mi)
#pragma unroll
                    for (int q = 0; q < 4; ++q) {
                        int row = mi * 16 + l4 * 4 + q;
                        int col = cb + nf * 16 + l15;
                        int ui = (col >> 3) ^ (row & 7);
                        int li = (row * 64 + ui) * 8 + (col & 7);
                        s1u[li] = f2b(va1[nf][mi][q]);
                        s2u[li] = f2b(va2[nf][mi][q]);
                    }
            if (w0 && l15 < 10) {
                ushortT* s0u = (ushortT*)s0S;
#pragma unroll
                for (int mi = 0; mi < 2; ++mi)
#pragma unroll
                    for (int q = 0; q < 4; ++q) {
                        int row = mi * 16 + l4 * 4 + q;
                        s0u[row * 32 + l15] = f2b(vaZ[mi][q]);
                    }
            }
            __syncthreads();
        } else {
            // final: write fp32 packed [4096,1034] = [s0 | s1 | s2]
#pragma unroll
            for (int nf = 0; nf < 4; ++nf)
#pragma unroll
                for (int mi = 0; mi < 2; ++mi)
#pragma unroll
                    for (int q = 0; q < 4; ++q) {
                        int row = mi * 16 + l4 * 4 + q;
                        int col = cb + nf * 16 + l15;
                        outF[(size_t)(bm + row) * CSTR + 10 + col] = va1[nf][mi][q];
                        outF[(size_t)(bm + row) * CSTR + 522 + col] = va2[nf][mi][q];
                    }
            if (w0 && l15 < 10) {
#pragma unroll
                for (int mi = 0; mi < 2; ++mi)
#pragma unroll
                    for (int q = 0; q < 4; ++q) {
                        int row = mi * 16 + l4 * 4 + q;
                        outF[(size_t)(bm + row) * CSTR + l15] = vaZ[mi][q];
                    }
            }
        }
    }
}

extern "C" void kernel_launch(void* const* d_in, const int* in_sizes, int n_in,
                              void* d_out, int out_size, void* d_ws, size_t ws_size,
                              hipStream_t stream) {
    const float* x  = (const float*)d_in[3];
    const float* W0 = (const float*)d_in[4];
    const float* b0 = (const float*)d_in[5];
    const float* W1 = (const float*)d_in[6];
    const float* b1 = (const float*)d_in[7];
    const float* W2 = (const float*)d_in[8];
    const float* b2 = (const float*)d_in[9];

    // ws: c2 f32 [4096*512] (8 MB) | pkZ1h/l, pkZ2h/l (512 KB each) | pkS0 32KB | pkZ0 16KB
    float* c2   = (float*)d_ws;
    u32x4* pkZ1h = (u32x4*)(c2 + (size_t)4096 * 512);
    u32x4* pkZ1l = pkZ1h + 32768;
    u32x4* pkZ2h = pkZ1l + 32768;
    u32x4* pkZ2l = pkZ2h + 32768;
    u32x4* pkS0  = pkZ2l + 32768;
    u32x4* pkZ0  = pkS0 + 2048;

    k_prep2<<<140, 256, 0, stream>>>(W1, W0, pkZ1h, pkZ1l, pkZ2h, pkZ2l, pkS0, pkZ0);
    k_c2<<<512, 256, 0, stream>>>(x, W2, b2, c2);
    k_main<<<128, 512, 0, stream>>>(pkZ1h, pkZ1l, pkZ2h, pkZ2l, pkS0, pkZ0,
                                    b0, b1, c2, (float*)d_out);
}

// Round 12
// 654.185 us; speedup vs baseline: 5.6828x; 5.6828x over previous
//
#include <hip/hip_runtime.h>

typedef unsigned short ushortT;
typedef short bf16x8 __attribute__((ext_vector_type(8)));
typedef float f32x4 __attribute__((ext_vector_type(4)));
typedef unsigned int u32x4 __attribute__((ext_vector_type(4)));

// EqProp free phase, B=4096, layers [10,512,512 | x=784 clamped], T=30, DT=0.5.
// States stay in [0,1] => rho(s)=s, rhop(s)=1.
// State: bf16 plane, row stride 1056: [0,10)=s0, [32,544)=s1, [544,1056)=s2.
// W1 split hi/lo bf16 (fp24). 30 launches of k_step4 = R6's proven 128x64-tile
// kernel widened to 512 threads / 8 waves per block (16 waves/CU) for latency
// hiding; traffic and numerics identical to R6 (absmax 0.0117).
#define HSTR 1056
#define OFF1B 32
#define OFF2B 544
#define CSTR 1034

__device__ __forceinline__ ushortT f2b(float f) {
    union { float f; unsigned u; } v; v.f = f;
    return (ushortT)((v.u + 0x7FFFu + ((v.u >> 16) & 1u)) >> 16);  // RNE
}
__device__ __forceinline__ float b2f(ushortT b) {
    union { unsigned u; float f; } v; v.u = ((unsigned)b) << 16;
    return v.f;
}
__device__ __forceinline__ void split2(float f, ushortT& h, ushortT& l) {
    h = f2b(f);
    l = f2b(f - b2f(h));
}

#define MFMA(a, b, c) __builtin_amdgcn_mfma_f32_16x16x32_bf16(a, b, c, 0, 0, 0)
#define BCAST(x) __builtin_bit_cast(bf16x8, x)

// ---------------- zero state buffer A ----------------
__global__ void k_zero(u32x4* __restrict__ p, int n) {
    u32x4 z = {0u, 0u, 0u, 0u};
    for (int i = blockIdx.x * blockDim.x + threadIdx.x; i < n; i += gridDim.x * blockDim.x)
        p[i] = z;
}

// ---------------- W1 -> split bf16 hi/lo, row-major + transpose (proven) ------------
__global__ __launch_bounds__(256) void k_prep(const float* __restrict__ W1,
                                              ushortT* __restrict__ W1h,
                                              ushortT* __restrict__ W1l,
                                              ushortT* __restrict__ W1Th,
                                              ushortT* __restrict__ W1Tl) {
    __shared__ float tile[64][65];
    const int ti = blockIdx.x >> 3, tj = blockIdx.x & 7;
    const int t = threadIdx.x;
#pragma unroll
    for (int q = 0; q < 16; ++q) {
        int rr = q * 4 + (t >> 6), cc = t & 63;
        float v = W1[(size_t)(ti * 64 + rr) * 512 + tj * 64 + cc];
        tile[rr][cc] = v;
        ushortT h, l; split2(v, h, l);
        W1h[(size_t)(ti * 64 + rr) * 512 + tj * 64 + cc] = h;
        W1l[(size_t)(ti * 64 + rr) * 512 + tj * 64 + cc] = l;
    }
    __syncthreads();
#pragma unroll
    for (int q = 0; q < 16; ++q) {
        int rr = q * 4 + (t >> 6), cc = t & 63;
        ushortT h, l; split2(tile[cc][rr], h, l);
        W1Th[(size_t)(tj * 64 + rr) * 512 + ti * 64 + cc] = h;
        W1Tl[(size_t)(tj * 64 + rr) * 512 + ti * 64 + cc] = l;
    }
}

// ---------------- c2 = rho(x) @ W2^T + b2 via split-bf16 MFMA (proven) ----------------
__global__ __launch_bounds__(256) void k_c2(const float* __restrict__ x,
                                            const float* __restrict__ W2,
                                            const float* __restrict__ b2,
                                            float* __restrict__ c2) {
    __shared__ u32x4 cs[2048];
    u32x4* xHi = cs;
    u32x4* xLo = cs + 512;
    u32x4* wHi = cs + 1024;
    u32x4* wLo = cs + 1536;
    const int bid = blockIdx.x, t = threadIdx.x;
    const int lane = t & 63, w = t >> 6, l15 = lane & 15, l4 = lane >> 4;
    const int bm2 = (bid >> 3) * 64, bn2 = (bid & 7) * 64;
    const int mB2 = (w >> 1) * 32, nB2 = (w & 1) * 32;
    const int sr2 = t >> 2, ub = (t & 3) * 2;
    f32x4 accC[2][2];
#pragma unroll
    for (int i = 0; i < 2; ++i)
#pragma unroll
        for (int j = 0; j < 2; ++j) { f32x4 z = {0.f, 0.f, 0.f, 0.f}; accC[i][j] = z; }
    for (int k0 = 0; k0 < 784; k0 += 64) {
#pragma unroll
        for (int j = 0; j < 2; ++j) {
            int u = ub + j;
            bool valid = (k0 + u * 8 + 8 <= 784);
            union { ushortT us[8]; u32x4 v; } ph, pl, qh, ql;
            if (valid) {
                const float* srcx = x  + (size_t)(bm2 + sr2) * 784 + k0 + u * 8;
                const float* srcw = W2 + (size_t)(bn2 + sr2) * 784 + k0 + u * 8;
#pragma unroll
                for (int e = 0; e < 8; ++e) {
                    float cx = fminf(fmaxf(srcx[e], 0.f), 1.f);
                    split2(cx, ph.us[e], pl.us[e]);
                    split2(srcw[e], qh.us[e], ql.us[e]);
                }
            } else {
#pragma unroll
                for (int e = 0; e < 8; ++e) { ph.us[e]=0; pl.us[e]=0; qh.us[e]=0; ql.us[e]=0; }
            }
            int sw = u ^ (sr2 & 7);
            xHi[sr2 * 8 + sw] = ph.v;  xLo[sr2 * 8 + sw] = pl.v;
            wHi[sr2 * 8 + sw] = qh.v;  wLo[sr2 * 8 + sw] = ql.v;
        }
        __syncthreads();
        int kwMax = (k0 == 768) ? 1 : 2;
        for (int kw = 0; kw < kwMax; ++kw) {
            bf16x8 ah[2], al[2], bh[2], bl[2];
#pragma unroll
            for (int i = 0; i < 2; ++i) {
                int m = mB2 + i * 16 + l15;
                int uu = (kw * 4 + l4) ^ (m & 7);
                ah[i] = BCAST(xHi[m * 8 + uu]);
                al[i] = BCAST(xLo[m * 8 + uu]);
                int n = nB2 + i * 16 + l15;
                int uv = (kw * 4 + l4) ^ (n & 7);
                bh[i] = BCAST(wHi[n * 8 + uv]);
                bl[i] = BCAST(wLo[n * 8 + uv]);
            }
#pragma unroll
            for (int i = 0; i < 2; ++i)
#pragma unroll
                for (int jj = 0; jj < 2; ++jj) {
                    accC[i][jj] = MFMA(ah[i], bh[jj], accC[i][jj]);
                    accC[i][jj] = MFMA(al[i], bh[jj], accC[i][jj]);
                    accC[i][jj] = MFMA(ah[i], bl[jj], accC[i][jj]);
                }
        }
        __syncthreads();
    }
#pragma unroll
    for (int mi = 0; mi < 2; ++mi)
#pragma unroll
        for (int ni = 0; ni < 2; ++ni)
#pragma unroll
            for (int q = 0; q < 4; ++q) {
                int row = bm2 + mB2 + mi * 16 + l4 * 4 + q;
                int col = bn2 + nB2 + ni * 16 + l15;
                c2[(size_t)row * 512 + col] = accC[mi][ni][q] + b2[col];
            }
}

// ---------------- per-step fused kernel: R6 structure, 8 waves/block ----------------
// 512 blocks x 512 thr. z1 (256 blocks): new s1 tile; z2 (256): new s2; z2&bn0 also z0.
// XCD affinity: xcd = bid&7 groups all consumers of a 128-row panel on one XCD.
__global__ __launch_bounds__(512, 4) void k_step4(const ushortT* __restrict__ sH,
                                                  ushortT* __restrict__ dH,
                                                  const ushortT* __restrict__ W1h,
                                                  const ushortT* __restrict__ W1l,
                                                  const ushortT* __restrict__ W1Th,
                                                  const ushortT* __restrict__ W1Tl,
                                                  const float* __restrict__ W0,
                                                  const float* __restrict__ b0,
                                                  const float* __restrict__ b1,
                                                  const float* __restrict__ c2,
                                                  float* __restrict__ outF) {
    __shared__ u32x4 smem[3072];     // 48 KiB
    u32x4* AsR = smem;               // 1024: A tile [128 rows][8 units], swizzled
    u32x4* BhS = smem + 1024;        //  512: W-hi tile [64][8]
    u32x4* BlS = smem + 1536;        //  512: W-lo tile [64][8]
    u32x4* aux = smem + 2048;        // 1024: doZ0 -> Bz0[16][64]; z1 -> Bs2[0..255]+As2[256..767]

    const int bid = blockIdx.x, t = threadIdx.x;
    const int lane = t & 63, w = t >> 6, l15 = lane & 15, l4 = lane >> 4;
    const int mB = w * 16;           // wave rows [mB, mB+16)

    const int xcd = bid & 7, rblk = bid >> 3, bn_i = rblk & 7, grp = rblk >> 3;
    const int pidx = grp * 8 + xcd;
    const bool isZ1 = pidx < 32;
    const int bm = (pidx & 31) * 128, bn = bn_i * 64;
    const bool doZ0 = (!isZ1) && (bn_i == 0);

    // ---- aux LDS staging (published by the K-loop's first barrier) ----
    if (isZ1) {
        if (t < 256) {   // Bs2[n][u]: B[n][k] = W0[k][bn+n], K=32 window (10 real)
            int n = t >> 2, u = t & 3;
            union { ushortT us[8]; u32x4 v; } pk;
#pragma unroll
            for (int e = 0; e < 8; ++e) {
                int k = u * 8 + e;
                pk.us[e] = (k < 10) ? f2b(W0[(size_t)k * 512 + bn + n]) : (ushortT)0;
            }
            aux[n * 4 + u] = pk.v;
        }
        if (t < 128) {   // As2[row][u]: s0 window, zero-padded to K=32
            union { ushortT us[16]; u32x4 v2[2]; } pk;
#pragma unroll
            for (int e = 0; e < 16; ++e) pk.us[e] = 0;
            const ushortT* sp = sH + (size_t)(bm + t) * HSTR;
#pragma unroll
            for (int e = 0; e < 10; ++e) pk.us[e] = sp[e];
            u32x4 z = {0u, 0u, 0u, 0u};
            aux[256 + t * 4 + 0] = pk.v2[0];
            aux[256 + t * 4 + 1] = pk.v2[1];
            aux[256 + t * 4 + 2] = z;
            aux[256 + t * 4 + 3] = z;
        }
    } else if (doZ0) {   // Bz0[c][64 units]: W0^T, 16 cols x K=512, swizzled
        int c = t >> 5, u0 = (t & 31) * 2;
#pragma unroll
        for (int j = 0; j < 2; ++j) {
            int U = u0 + j;
            union { ushortT us[8]; u32x4 v; } pk;
#pragma unroll
            for (int e = 0; e < 8; ++e)
                pk.us[e] = (c < 10) ? f2b(W0[(size_t)c * 512 + U * 8 + e]) : (ushortT)0;
            aux[c * 64 + ((U & ~7) | ((U & 7) ^ (c & 7)))] = pk.v;
        }
    }

    const int aOff = isZ1 ? OFF2B : OFF1B;   // z1 reads s2, z2 reads s1
    const int dOff = isZ1 ? OFF1B : OFF2B;   // dest layer
    const int oOff = isZ1 ? 10 : 522;
    const ushortT* __restrict__ Wbh = isZ1 ? W1h : W1Th;
    const ushortT* __restrict__ Wbl = isZ1 ? W1l : W1Tl;
    const int sr = t >> 2, su = (t & 3) * 2;     // A staging: 4 thr/row, 2 units each
    const int bnr = t >> 3, bju = t & 7;         // B staging: 8 thr/row, 1 unit each
    const bool fin = (outF != nullptr);

    f32x4 acc[4], accZ;
#pragma unroll
    for (int ni = 0; ni < 4; ++ni) { f32x4 z = {0.f,0.f,0.f,0.f}; acc[ni] = z; }
    { f32x4 z = {0.f,0.f,0.f,0.f}; accZ = z; }

    // ---- software-pipelined K loop: 8 iters of BK=64, reg-staged double buffer ----
    u32x4 rA[2][2], rBh[2], rBl[2];
    {
        const u32x4* gA = (const u32x4*)(sH + (size_t)(bm + sr) * HSTR + aOff);
        rA[0][0] = gA[su];  rA[0][1] = gA[su + 1];
        rBh[0] = ((const u32x4*)(Wbh + (size_t)(bn + bnr) * 512))[bju];
        rBl[0] = ((const u32x4*)(Wbl + (size_t)(bn + bnr) * 512))[bju];
    }
#pragma unroll
    for (int it = 0; it < 8; ++it) {
        const int k0 = it * 64;
        const int cur = it & 1, nxt = cur ^ 1;
        __syncthreads();                      // prev compute done; LDS reusable
        AsR[sr * 8 + ( su      ^ (sr & 7))] = rA[cur][0];
        AsR[sr * 8 + ((su + 1) ^ (sr & 7))] = rA[cur][1];
        BhS[bnr * 8 + (bju ^ (bnr & 7))] = rBh[cur];
        BlS[bnr * 8 + (bju ^ (bnr & 7))] = rBl[cur];
        if (it < 7) {                         // prefetch next K tile into regs
            const int k1 = k0 + 64;
            const u32x4* gA = (const u32x4*)(sH + (size_t)(bm + sr) * HSTR + aOff + k1);
            rA[nxt][0] = gA[su];  rA[nxt][1] = gA[su + 1];
            rBh[nxt] = ((const u32x4*)(Wbh + (size_t)(bn + bnr) * 512 + k1))[bju];
            rBl[nxt] = ((const u32x4*)(Wbl + (size_t)(bn + bnr) * 512 + k1))[bju];
        }
        __syncthreads();                      // publish LDS
#pragma unroll
        for (int kw = 0; kw < 2; ++kw) {
            bf16x8 a, bh[4], bl[4];
            {
                int m = mB + l15;
                a = BCAST(AsR[m * 8 + ((kw * 4 + l4) ^ (m & 7))]);
            }
#pragma unroll
            for (int ni = 0; ni < 4; ++ni) {
                int n = ni * 16 + l15;
                int u = (kw * 4 + l4) ^ (n & 7);
                bh[ni] = BCAST(BhS[n * 8 + u]);
                bl[ni] = BCAST(BlS[n * 8 + u]);
            }
#pragma unroll
            for (int ni = 0; ni < 4; ++ni) {
                acc[ni] = MFMA(a, bh[ni], acc[ni]);
                acc[ni] = MFMA(a, bl[ni], acc[ni]);
            }
            if (doZ0) {
                int U = it * 8 + kw * 4 + l4;
                bf16x8 bz = BCAST(aux[l15 * 64 + ((U & ~7) | ((U & 7) ^ (l15 & 7)))]);
                accZ = MFMA(a, bz, accZ);
            }
        }
    }
    if (isZ1) {   // s0 @ W0 extra K=32 window
        bf16x8 a2 = BCAST(aux[256 + (size_t)(mB + l15) * 4 + l4]);
#pragma unroll
        for (int ni = 0; ni < 4; ++ni) {
            bf16x8 bb = BCAST(aux[(size_t)(ni * 16 + l15) * 4 + l4]);
            acc[ni] = MFMA(a2, bb, acc[ni]);
        }
    }

    // ---- epilogue: v = clip(0.5*old + 0.5*(acc + bias)) ----
    __syncthreads();   // all LDS reads done; AsR reusable as output staging
    if (fin) {
#pragma unroll
        for (int ni = 0; ni < 4; ++ni) {
            int gc = bn + ni * 16 + l15;
            float biasN = isZ1 ? b1[gc] : 0.f;
#pragma unroll
            for (int q = 0; q < 4; ++q) {
                size_t row = (size_t)bm + mB + l4 * 4 + q;
                float bias = isZ1 ? biasN : c2[row * 512 + gc];
                float old = b2f(sH[row * HSTR + dOff + gc]);
                float v = 0.5f * old + 0.5f * (acc[ni][q] + bias);
                v = fminf(fmaxf(v, 0.f), 1.f);
                outF[row * CSTR + oOff + gc] = v;
            }
        }
        if (doZ0 && l15 < 10) {
            float b0v = b0[l15];
#pragma unroll
            for (int q = 0; q < 4; ++q) {
                size_t row = (size_t)bm + mB + l4 * 4 + q;
                float old = b2f(sH[row * HSTR + l15]);
                float v = 0.5f * old + 0.5f * (accZ[q] + b0v);
                v = fminf(fmaxf(v, 0.f), 1.f);
                outF[row * CSTR + l15] = v;
            }
        }
    } else {
        ushortT* dlds = (ushortT*)AsR;   // 128x64 bf16 output tile
#pragma unroll
        for (int ni = 0; ni < 4; ++ni) {
            int gc = bn + ni * 16 + l15;
            float biasN = isZ1 ? b1[gc] : 0.f;
#pragma unroll
            for (int q = 0; q < 4; ++q) {
                size_t row = (size_t)bm + mB + l4 * 4 + q;
                float bias = isZ1 ? biasN : c2[row * 512 + gc];
                float old = b2f(sH[row * HSTR + dOff + gc]);
                float v = 0.5f * old + 0.5f * (acc[ni][q] + bias);
                v = fminf(fmaxf(v, 0.f), 1.f);
                dlds[(mB + l4 * 4 + q) * 64 + ni * 16 + l15] = f2b(v);
            }
        }
        if (doZ0 && l15 < 10) {
            float b0v = b0[l15];
#pragma unroll
            for (int q = 0; q < 4; ++q) {
                size_t row = (size_t)bm + mB + l4 * 4 + q;
                float old = b2f(sH[row * HSTR + l15]);
                float v = 0.5f * old + 0.5f * (accZ[q] + b0v);
                v = fminf(fmaxf(v, 0.f), 1.f);
                dH[row * HSTR + l15] = f2b(v);
            }
        }
        __syncthreads();
        // coalesced 16B-per-lane tile store into this block's column slice
#pragma unroll
        for (int j = 0; j < 2; ++j) {
            int i = j * 512 + t;
            int row = i >> 3, u = i & 7;
            ((u32x4*)(dH + (size_t)(bm + row) * HSTR + dOff + bn))[u] = AsR[i];
        }
    }
}

extern "C" void kernel_launch(void* const* d_in, const int* in_sizes, int n_in,
                              void* d_out, int out_size, void* d_ws, size_t ws_size,
                              hipStream_t stream) {
    const float* x  = (const float*)d_in[3];
    const float* W0 = (const float*)d_in[4];
    const float* b0 = (const float*)d_in[5];
    const float* W1 = (const float*)d_in[6];
    const float* b1 = (const float*)d_in[7];
    const float* W2 = (const float*)d_in[8];
    const float* b2 = (const float*)d_in[9];

    // buffer A in d_out: 4096*1056*2 = 8,650,752 B <= 16,943,104 B
    ushortT* hiA = (ushortT*)d_out;
    // ws: hiB | c2 f32 | W1h | W1l | W1Th | W1Tl  (~19.1 MB)
    ushortT* hiB = (ushortT*)d_ws;
    float*   c2  = (float*)(hiB + (size_t)4096 * HSTR);
    ushortT* W1h = (ushortT*)(c2 + (size_t)4096 * 512);
    ushortT* W1l  = W1h + 512 * 512;
    ushortT* W1Th = W1l + 512 * 512;
    ushortT* W1Tl = W1Th + 512 * 512;

    const int zeroN = (int)((size_t)4096 * HSTR * sizeof(ushortT) / sizeof(u32x4));
    k_zero<<<1024, 256, 0, stream>>>((u32x4*)hiA, zeroN);
    k_prep<<<64, 256, 0, stream>>>(W1, W1h, W1l, W1Th, W1Tl);
    k_c2<<<512, 256, 0, stream>>>(x, W2, b2, c2);

    for (int ts = 0; ts < 30; ++ts) {
        const ushortT* sH = (ts & 1) ? hiB : hiA;
        ushortT* dH       = (ts & 1) ? hiA : hiB;
        float* outF = (ts == 29) ? (float*)d_out : nullptr;
        k_step4<<<512, 512, 0, stream>>>(sH, dH, W1h, W1l, W1Th, W1Tl,
                                         W0, b0, b1, c2, outF);
    }
}